// Round 14
// baseline (158.386 us; speedup 1.0000x reference)
//
#include <hip/hip_runtime.h>

// NRC fused encode + 7-layer W=64 MLP. R14: intra-wave software pipeline —
// encode(batch b+1) overlaps layers(batch b) inside one wave.
//
// Cross-round ledger: VALU-pipe total ~28.5us and MFMA-pipe total ~22us are
// invariant R10->R13, and dur ~= SUM (zero pipe overlap: phase-locked waves).
// R14 makes overlap structural: each wave runs NB=4 batches of 64 samples;
// batch b+1's encode (independent VALU) is placed inside batch b's barrier-
// free layer window so the scheduler fills MFMA shadows. Floor: max(28.5,22).
//
// LDS (65536B = 2 blocks/CU): [0,49152) hidden-weight image (units 0..47),
// [49152,+8*2048) per-wave staging slices. W6 frags live in registers.
// One __syncthreads total (after cooperative weight stage).
//
// 16x16x32 f16 fragment maps (verified):
//   A[m=lane&15][k=(lane>>4)*8+j], B[k=(lane>>4)*8+j][n=lane&15],
//   D[row=(lane>>4)*4+r][col=lane&15]  (4 blocks mt: row=mt*16+q*4+r)
// Chaining: bf[kt]=concat(relu(pack(acc[2kt])), relu(pack(acc[2kt+1])));
// k-index mismatch absorbed by permuting W1..W5,W6 columns with
// tau(x)=32(x>>5)+16((x&7)>>2)+4((x>>3)&3)+(x&3) at pack time.

typedef _Float16 f16;
typedef f16 f16x2 __attribute__((ext_vector_type(2)));
typedef f16 f16x4 __attribute__((ext_vector_type(4)));
typedef f16 f16x8 __attribute__((ext_vector_type(8)));
typedef float f32x4 __attribute__((ext_vector_type(4)));

#define MFMA32(A, B, C) __builtin_amdgcn_mfma_f32_16x16x32_f16(A, B, C, 0, 0, 0)
#define LDS_FENCE() __asm__ volatile("" ::: "memory")

static constexpr int TILES = 4;            // 16-sample tiles per batch
static constexpr int WAVES = 8;            // waves per block
static constexpr int BLOCK = WAVES * 64;   // 512
static constexpr int NB    = 4;            // 64-sample batches per wave
static constexpr int SPW   = 64 * NB;      // 256 samples per wave
static constexpr int SPB   = WAVES * SPW;  // 2048 samples per block

static constexpr int    WUNITS   = 50;     // 48 hidden + 2 W6 frag-units
static constexpr int    WCHUNKS  = WUNITS * 64;          // 3200
static constexpr int    HCHUNKS  = 48 * 64;              // 3072 hidden chunks
static constexpr size_t WS_BYTES = (size_t)WCHUNKS * 16; // 51200
static constexpr int    LDS_H    = 48 * 1024;            // 49152

__host__ __device__ __forceinline__ int tau(int x) {
    return (x & 32) + ((x & 7) >> 2) * 16 + ((x >> 3) & 3) * 4 + (x & 3);
}

__device__ __forceinline__ f16x2 pkh(float a, float b) {
    return __builtin_bit_cast(f16x2, __builtin_amdgcn_cvt_pkrtz(a, b));
}

__device__ __forceinline__ f16x8 pack8(const float* f) {
    f16x2 a = pkh(f[0], f[1]);
    f16x2 b = pkh(f[2], f[3]);
    f16x2 c = pkh(f[4], f[5]);
    f16x2 d = pkh(f[6], f[7]);
    f16x8 v;
    v[0] = a[0]; v[1] = a[1]; v[2] = b[0]; v[3] = b[1];
    v[4] = c[0]; v[5] = c[1]; v[6] = d[0]; v[7] = d[1];
    return v;
}

__device__ __forceinline__ f16x4 pack4(f32x4 v) {
    f16x2 a = pkh(v[0], v[1]);
    f16x2 b = pkh(v[2], v[3]);
    f16x4 r;
    r[0] = a[0]; r[1] = a[1]; r[2] = b[0]; r[3] = b[1];
    return r;
}

// atan2(y,x) / (2*pi)
__device__ __forceinline__ float fast_atan2_rev(float y, float x) {
    const float ax = __builtin_fabsf(x), ay = __builtin_fabsf(y);
    const float mx = fmaxf(ax, ay), mn = fminf(ax, ay);
    const float a = mn * __builtin_amdgcn_rcpf(fmaxf(mx, 1e-30f));
    const float s = a * a;
    float r = a * (0.99997726f + s * (-0.33262347f + s * (0.19354346f +
              s * (-0.11643287f + s * (0.05265332f - s * 0.01172120f)))));
    if (ay > ax) r = 1.5707963268f - r;
    if (x < 0.0f) r = 3.1415926536f - r;
    r = (y < 0.0f) ? -r : r;
    return r * 0.15915494309189535f;
}

// acos(x), |err| <= 6.8e-5 rad
__device__ __forceinline__ float fast_acos(float x) {
    const float ax = __builtin_fabsf(x);
    const float t = __builtin_amdgcn_sqrtf(1.0f - ax);
    const float p = t * (1.5707288f + ax * (-0.2121144f +
                    ax * (0.0742610f - ax * 0.0187293f)));
    return (x < 0.0f) ? (3.1415926536f - p) : p;
}

// one-blob: out[i]=exp(-8(x-c_i)^2) via exp ladder (2 transcendentals)
__device__ __forceinline__ void blob4(float x, float* out) {
    const float dx = x - 0.125f;
    const float E0 = __expf(-8.0f * dx * dx);
    const float R  = __expf(4.0f * dx);
    const float t1 = R * 0.60653066f;
    const float t2 = R * 0.22313016f;
    const float t3 = R * 0.082084999f;
    out[0] = E0;
    out[1] = E0 * t1;
    out[2] = out[1] * t2;
    out[3] = out[2] * t3;
}

// compute packed-weight chunk c (= unit*64 + lane2) from the f32 weights
__device__ __forceinline__ f16x8 make_wchunk(
    int c, const float* __restrict__ W0, const float* __restrict__ W1,
    const float* __restrict__ W2, const float* __restrict__ W3,
    const float* __restrict__ W4, const float* __restrict__ W5,
    const float* __restrict__ W6)
{
    const int lane2 = c & 63;
    const int unit  = c >> 6;
    const int q = lane2 >> 4, m = lane2 & 15;
    f16x8 v;
    if (unit < 48) {
        const int l = unit >> 3, kt = (unit & 7) >> 2, mt = unit & 3;
        const float* Ws[6] = {W0, W1, W2, W3, W4, W5};
        const float* __restrict__ Wl = Ws[l];
#pragma unroll
        for (int j = 0; j < 8; ++j) {
            const int x = kt * 32 + q * 8 + j;
            const int src = (l == 0) ? x : tau(x);
            v[j] = (f16)Wl[(mt * 16 + m) * 64 + src];
        }
    } else {
        const int kt = unit - 48;
#pragma unroll
        for (int j = 0; j < 8; ++j) {
            const int src = tau(kt * 32 + q * 8 + j);
            v[j] = (m < 3) ? (f16)W6[m * 64 + src] : (f16)0.0f;
        }
    }
    return v;
}

__global__ __launch_bounds__(256, 1) void pack_weights_kernel(
    const float* __restrict__ W0, const float* __restrict__ W1,
    const float* __restrict__ W2, const float* __restrict__ W3,
    const float* __restrict__ W4, const float* __restrict__ W5,
    const float* __restrict__ W6, f16* __restrict__ ws)
{
    const int c = (int)blockIdx.x * 256 + threadIdx.x;
    if (c >= WCHUNKS) return;
    *(f16x8*)(ws + (size_t)c * 8) = make_wchunk(c, W0, W1, W2, W3, W4, W5, W6);
}

__device__ __forceinline__ f16x8 cat44(f16x4 a, f16x4 b) {
    return __builtin_shufflevector(a, b, 0, 1, 2, 3, 4, 5, 6, 7);
}

// full 64-feature encode of one sample -> 8 pre-packed f16x8 chunks + ab
__device__ __forceinline__ void encode64(
    const float pv[3], const float wv[3], const float nv[3],
    const float av[3], const float bv[3], float rv,
    f16x8 fh[8], float& ab0, float& ab1, float& ab2)
{
    float feat[64];
#pragma unroll
    for (int d = 0; d < 3; ++d) {
        const float fr = __builtin_amdgcn_fractf(pv[d] * 0.5f);
        float sv = __builtin_amdgcn_sinf(fr);
        float cv = __builtin_amdgcn_cosf(fr);
        feat[d * 12 + 0] = sv;
        feat[d * 12 + 6] = cv;
#pragma unroll
        for (int k = 1; k < 6; ++k) {
            const float s2 = sv * sv;
            const float sc = sv * cv;
            cv = fmaf(-2.0f, s2, 1.0f);
            sv = sc + sc;
            feat[d * 12 + k]     = sv;
            feat[d * 12 + 6 + k] = cv;
        }
    }
#pragma unroll
    for (int which = 0; which < 2; ++which) {
        const float* dv = (which == 0) ? wv : nv;
        const int fo = 36 + which * 8;
        const float nr = __builtin_amdgcn_sqrtf(dv[0]*dv[0] + dv[1]*dv[1] + dv[2]*dv[2]) + 1e-8f;
        const float u  = fast_atan2_rev(dv[1], dv[0]) + 0.5f;
        float zc = dv[2] * __builtin_amdgcn_rcpf(nr);
        zc = fminf(fmaxf(zc, -1.0f + 1e-6f), 1.0f - 1e-6f);
        const float vv = fast_acos(zc) * 0.3183098861837907f;
        blob4(u,  &feat[fo]);
        blob4(vv, &feat[fo + 4]);
    }
    blob4(1.0f - __expf(-rv), &feat[52]);

    feat[56] = av[0]; feat[57] = av[1]; feat[58] = av[2];
    feat[59] = bv[0]; feat[60] = bv[1]; feat[61] = bv[2];
    feat[62] = 1.0f;  feat[63] = 1.0f;

    ab0 = av[0] + bv[0];
    ab1 = av[1] + bv[1];
    ab2 = av[2] + bv[2];

#pragma unroll
    for (int g = 0; g < 8; ++g) fh[g] = pack8(&feat[g * 8]);
}

template<int PACKED>
__global__ __launch_bounds__(BLOCK, 3) void nrc_mlp_kernel(
    const float* __restrict__ P,  const float* __restrict__ WI,
    const float* __restrict__ NV, const float* __restrict__ AL,
    const float* __restrict__ BE, const float* __restrict__ RR,
    const f16*   __restrict__ ws,
    const float* __restrict__ W0, const float* __restrict__ W1,
    const float* __restrict__ W2, const float* __restrict__ W3,
    const float* __restrict__ W4, const float* __restrict__ W5,
    const float* __restrict__ W6, float* __restrict__ Out)
{
    // [0, 49152): hidden-weight image | [49152, 65536): 8 x 2048B staging
    __shared__ __attribute__((aligned(16))) unsigned char smem[LDS_H + WAVES * 2048];

    const int tid  = threadIdx.x;
    const int lane = tid & 63;
    const int w    = tid >> 6;
    const int q    = lane >> 4;
    const int m    = lane & 15;
    unsigned char* const hb = smem + LDS_H + w * 2048;

    const int wave_samp0 = ((int)blockIdx.x * WAVES + w) * SPW;

    // ---- cooperative hidden-weight stage (3072 chunks / 512 thr = 6 it) ----
#pragma unroll
    for (int i = 0; i < HCHUNKS / BLOCK; ++i) {
        const int c = i * BLOCK + tid;
        f16x8 v;
        if (PACKED) v = *(const f16x8*)(ws + (size_t)c * 8);
        else        v = make_wchunk(c, W0, W1, W2, W3, W4, W5, W6);
        *(f16x8*)(smem + c * 16) = v;
    }

    // ---- W6 frags in registers (tau-permuted cols, rows padded to 16) ----
    f16x8 w6f0, w6f1;
    if (PACKED) {
        w6f0 = *(const f16x8*)(ws + 48 * 512 + (size_t)lane * 8);
        w6f1 = *(const f16x8*)(ws + 49 * 512 + (size_t)lane * 8);
    } else {
        float t0[8], t1[8];
#pragma unroll
        for (int j = 0; j < 8; ++j) {
            t0[j] = (m < 3) ? W6[m * 64 + tau(q * 8 + j)]      : 0.0f;
            t1[j] = (m < 3) ? W6[m * 64 + tau(32 + q * 8 + j)] : 0.0f;
        }
        w6f0 = pack8(t0);
        w6f1 = pack8(t1);
    }

    f16x8 bf[TILES][2];
    f16x8 fh[8];
    float abc0, abc1, abc2, abn0, abn1, abn2;

    // ---- prologue: encode + stage batch 0 ----
    {
        const int s = wave_samp0 + lane;
        float pv[3], wv[3], nv[3], av[3], bv[3];
#pragma unroll
        for (int d = 0; d < 3; ++d) {
            pv[d] = P [s * 3 + d];
            wv[d] = WI[s * 3 + d];
            nv[d] = NV[s * 3 + d];
            av[d] = AL[s * 3 + d];
            bv[d] = BE[s * 3 + d];
        }
        encode64(pv, wv, nv, av, bv, RR[s], fh, abn0, abn1, abn2);
    }
#pragma unroll
    for (int pass = 0; pass < TILES; ++pass) {
        if ((lane >> 4) == pass) {
            unsigned char* const tb = hb + m * 128;
#pragma unroll
            for (int g = 0; g < 8; ++g)
                *(f16x8*)(tb + ((4 * g + 4 * m) & 31) * 4) = fh[g];
        }
        LDS_FENCE();
#pragma unroll
        for (int kt = 0; kt < 2; ++kt)
            bf[pass][kt] = *(const f16x8*)(hb + m * 128 + ((16 * kt + 4 * q + 4 * m) & 31) * 4);
        LDS_FENCE();
    }
    abc0 = abn0; abc1 = abn1; abc2 = abn2;

    __syncthreads();   // weight image complete before layer ds_reads

    const f16x4 zero4 = {(f16)0.0f, (f16)0.0f, (f16)0.0f, (f16)0.0f};

    // ---- pipelined batches: layers(b) overlap encode(b+1) ----
#pragma unroll
    for (int b = 0; b < NB; ++b) {
        const bool more = (b + 1 < NB);

        // inputs for next batch (issued early; compiler hoists loads)
        float pv[3], wv[3], nv[3], av[3], bv[3], rvv = 0.0f;
        if (more) {
            const int s = wave_samp0 + (b + 1) * 64 + lane;
#pragma unroll
            for (int d = 0; d < 3; ++d) {
                pv[d] = P [s * 3 + d];
                wv[d] = WI[s * 3 + d];
                nv[d] = NV[s * 3 + d];
                av[d] = AL[s * 3 + d];
                bv[d] = BE[s * 3 + d];
            }
            rvv = RR[s];
        }

        // layers 0..1
#pragma unroll
        for (int layer = 0; layer < 2; ++layer) {
            f16x8 wa[8];
#pragma unroll
            for (int f = 0; f < 8; ++f)
                wa[f] = *(const f16x8*)(smem + (layer * 8 + f) * 1024 + lane * 16);
#pragma unroll
            for (int t = 0; t < TILES; ++t) {
                f32x4 acc[4];
#pragma unroll
                for (int mt = 0; mt < 4; ++mt) {
                    f32x4 z = {0.0f, 0.0f, 0.0f, 0.0f};
                    z = MFMA32(wa[mt],     bf[t][0], z);
                    z = MFMA32(wa[4 + mt], bf[t][1], z);
                    acc[mt] = z;
                }
                f16x4 pk[4];
#pragma unroll
                for (int mt = 0; mt < 4; ++mt)
                    pk[mt] = __builtin_elementwise_max(pack4(acc[mt]), zero4);
                bf[t][0] = cat44(pk[0], pk[1]);
                bf[t][1] = cat44(pk[2], pk[3]);
            }
        }

        // encode(b+1): independent VALU, scheduled into MFMA shadows
        if (more) encode64(pv, wv, nv, av, bv, rvv, fh, abn0, abn1, abn2);

        // layers 2..5
#pragma unroll
        for (int layer = 2; layer < 6; ++layer) {
            f16x8 wa[8];
#pragma unroll
            for (int f = 0; f < 8; ++f)
                wa[f] = *(const f16x8*)(smem + (layer * 8 + f) * 1024 + lane * 16);
#pragma unroll
            for (int t = 0; t < TILES; ++t) {
                f32x4 acc[4];
#pragma unroll
                for (int mt = 0; mt < 4; ++mt) {
                    f32x4 z = {0.0f, 0.0f, 0.0f, 0.0f};
                    z = MFMA32(wa[mt],     bf[t][0], z);
                    z = MFMA32(wa[4 + mt], bf[t][1], z);
                    acc[mt] = z;
                }
                f16x4 pk[4];
#pragma unroll
                for (int mt = 0; mt < 4; ++mt)
                    pk[mt] = __builtin_elementwise_max(pack4(acc[mt]), zero4);
                bf[t][0] = cat44(pk[0], pk[1]);
                bf[t][1] = cat44(pk[2], pk[3]);
            }
        }

        // W6 + scale by (alpha+beta) of batch b
#pragma unroll
        for (int t = 0; t < TILES; ++t) {
            f32x4 z = {0.0f, 0.0f, 0.0f, 0.0f};
            z = MFMA32(w6f0, bf[t][0], z);
            z = MFMA32(w6f1, bf[t][1], z);
            const int src = t * 16 + m;
            const float s0 = __shfl(abc0, src);
            const float s1 = __shfl(abc1, src);
            const float s2 = __shfl(abc2, src);
            if (lane < 16) {
                const int s = wave_samp0 + b * 64 + t * 16 + m;
                float* o = Out + s * 3;
                o[0] = z[0] * s0;
                o[1] = z[1] * s1;
                o[2] = z[2] * s2;
            }
        }

        // stage batch b+1 into bf
        if (more) {
#pragma unroll
            for (int pass = 0; pass < TILES; ++pass) {
                if ((lane >> 4) == pass) {
                    unsigned char* const tb = hb + m * 128;
#pragma unroll
                    for (int g = 0; g < 8; ++g)
                        *(f16x8*)(tb + ((4 * g + 4 * m) & 31) * 4) = fh[g];
                }
                LDS_FENCE();
#pragma unroll
                for (int kt = 0; kt < 2; ++kt)
                    bf[pass][kt] = *(const f16x8*)(hb + m * 128 + ((16 * kt + 4 * q + 4 * m) & 31) * 4);
                LDS_FENCE();
            }
            abc0 = abn0; abc1 = abn1; abc2 = abn2;
        }
    }
}

extern "C" void kernel_launch(void* const* d_in, const int* in_sizes, int n_in,
                              void* d_out, int out_size, void* d_ws, size_t ws_size,
                              hipStream_t stream) {
    (void)n_in; (void)out_size;
    const float* P  = (const float*)d_in[0];
    const float* WI = (const float*)d_in[1];
    const float* NV = (const float*)d_in[2];
    const float* AL = (const float*)d_in[3];
    const float* BE = (const float*)d_in[4];
    const float* RR = (const float*)d_in[5];
    const float* W0 = (const float*)d_in[6];
    const float* W1 = (const float*)d_in[7];
    const float* W2 = (const float*)d_in[8];
    const float* W3 = (const float*)d_in[9];
    const float* W4 = (const float*)d_in[10];
    const float* W5 = (const float*)d_in[11];
    const float* W6 = (const float*)d_in[12];
    f16*   ws  = (f16*)d_ws;
    float* Out = (float*)d_out;

    const int Bn = in_sizes[0] / 3;     // 1,048,576
    const int grid = Bn / SPB;          // 512 blocks of 512 threads

    // ws_size fixed per session -> same path every call (graph-safe).
    if (ws_size >= WS_BYTES) {
        hipLaunchKernelGGL(pack_weights_kernel, dim3((WCHUNKS + 255) / 256),
                           dim3(256), 0, stream, W0, W1, W2, W3, W4, W5, W6, ws);
        hipLaunchKernelGGL((nrc_mlp_kernel<1>), dim3(grid), dim3(BLOCK), 0, stream,
                           P, WI, NV, AL, BE, RR, ws,
                           W0, W1, W2, W3, W4, W5, W6, Out);
    } else {
        hipLaunchKernelGGL((nrc_mlp_kernel<0>), dim3(grid), dim3(BLOCK), 0, stream,
                           P, WI, NV, AL, BE, RR, ws,
                           W0, W1, W2, W3, W4, W5, W6, Out);
    }
}